// Round 1
// baseline (1395.598 us; speedup 1.0000x reference)
//
#include <hip/hip_runtime.h>
#include <hip/hip_bf16.h>
#include <stdint.h>

#define B_Q     2
#define N_TOK   131072        // 128*128*8
#define C_DIM   128
#define N_HEADS 8
#define S_VAL   9507          // 7191 + 1848 + 468
#define PSS     292           // padded row stride for P tile (288 cols)

// ---------------------------------------------------------------------------
// K0: scatter voxel mask. mask[b*N + flat] = 1 for in-bounds vol_pts.
// ---------------------------------------------------------------------------
__global__ __launch_bounds__(256) void mask_scatter_kernel(
    const int* __restrict__ vol, int* __restrict__ mask)
{
    int i = blockIdx.x * 256 + threadIdx.x;      // over B*N
    if (i >= B_Q * N_TOK) return;
    int b = i / N_TOK;
    const int* p = vol + (size_t)i * 3;
    int x = p[0], y = p[1], z = p[2];
    if (x >= 0 && x < 128 && y >= 0 && y < 128 && z >= 0 && z < 8)
        mask[b * N_TOK + x * 1024 + y * 8 + z] = 1;
}

// ---------------------------------------------------------------------------
// K1: value projection. value_bf16[b][s][c] = (featcat[b][s][:] . Wv[:,c]) + bv[c]
// featcat[b][s][k] = feat_l[b][k][pos]  (A^T layout in memory).
// Block: 64 s-rows x 128 cols, 256 threads.
// ---------------------------------------------------------------------------
__global__ __launch_bounds__(256) void value_proj_kernel(
    const float* __restrict__ f0, const float* __restrict__ f1,
    const float* __restrict__ f2,
    const float* __restrict__ Wv, const float* __restrict__ bv,
    __hip_bfloat16* __restrict__ value)
{
    __shared__ float Ast[128 * 68];   // A^T tile: [k][j], stride 68 (pad)

    int blk = blockIdx.x;
    int b   = blk / 149;
    int s0  = (blk % 149) * 64;
    int t   = threadIdx.x;

    // --- load A^T: thread t handles j = t%64, k = t/64 + 4*i ---
    int j = t & 63;
    int a = t >> 6;
    int s = s0 + j;
    #pragma unroll
    for (int i = 0; i < 32; ++i) {
        int k = a + 4 * i;
        float v = 0.f;
        if (s < S_VAL) {
            if (s < 7191)      v = f0[((size_t)b * 128 + k) * 7191 + s];
            else if (s < 9039) v = f1[((size_t)b * 128 + k) * 1848 + (s - 7191)];
            else               v = f2[((size_t)b * 128 + k) * 468  + (s - 9039)];
        }
        Ast[k * 68 + j] = v;
    }
    __syncthreads();

    // --- compute: thread t -> col c = t%128, row-group rg = t/128 (32 rows) ---
    int c  = t & 127;
    int rg = t >> 7;
    float acc[32];
    #pragma unroll
    for (int i = 0; i < 32; ++i) acc[i] = 0.f;

    for (int k = 0; k < 128; ++k) {
        float wv = Wv[k * 128 + c];
        const float4* arow = (const float4*)&Ast[k * 68 + rg * 32];
        #pragma unroll
        for (int ii = 0; ii < 8; ++ii) {
            float4 av = arow[ii];
            acc[4 * ii + 0] += av.x * wv;
            acc[4 * ii + 1] += av.y * wv;
            acc[4 * ii + 2] += av.z * wv;
            acc[4 * ii + 3] += av.w * wv;
        }
    }
    float bvc = bv[c];
    #pragma unroll
    for (int i = 0; i < 32; ++i) {
        int s2 = s0 + rg * 32 + i;
        if (s2 < S_VAL)
            value[((size_t)b * S_VAL + s2) * 128 + c] = __float2bfloat16(acc[i] + bvc);
    }
}

// ---------------------------------------------------------------------------
// K2 mega-kernel: per block of 32 tokens:
//   Ph1: q = embed + pos -> LDS
//   Ph2: P = q @ [Woff|Ww] + bias  (288 cols) -> LDS
//   Ph2b: softmax over each (head, 12) weight group
//   Ph3: bilinear sampling from bf16 value -> per-(token,head) 16-dim acc
//   Ph4: out = acc @ Wo + bo + identity; LayerNorm; mask-select
//   Ph5: transposed coalesced store to (B, C, N)
// ---------------------------------------------------------------------------
__global__ __launch_bounds__(256) void fused_kernel(
    const float* __restrict__ embed, const float* __restrict__ pos,
    const float* __restrict__ refpix,
    const float* __restrict__ Woff, const float* __restrict__ boff,
    const float* __restrict__ Ww,   const float* __restrict__ bw,
    const float* __restrict__ Wo,   const float* __restrict__ bo,
    const float* __restrict__ ln_g, const float* __restrict__ ln_b,
    const __hip_bfloat16* __restrict__ value,
    const int* __restrict__ mask,
    float* __restrict__ out)
{
    __shared__ float es[32 * 132];   // scene_embed tile (identity), padded
    __shared__ float u1[32 * 132];   // q tile, later acc tile
    __shared__ float u2[32 * PSS];   // P tile, later out-transpose tile (128*33)

    int t     = threadIdx.x;
    int bb    = blockIdx.x;
    int b     = bb >> 12;            // 4096 blocks per batch sample
    int tbase = (bb & 4095) * 32;

    // ---------------- Ph1: load embed & pos, q = e + p ----------------
    {
        const float4* e4 = (const float4*)embed + ((size_t)b * N_TOK + tbase) * 32;
        const float4* p4 = (const float4*)pos   + ((size_t)b * N_TOK + tbase) * 32;
        #pragma unroll
        for (int i = 0; i < 4; ++i) {
            int idx = t + 256 * i;           // 0..1023 float4s
            int r = idx >> 5, k4 = idx & 31;
            float4 e = e4[idx];
            float4 p = p4[idx];
            int base = r * 132 + k4 * 4;
            es[base + 0] = e.x; es[base + 1] = e.y; es[base + 2] = e.z; es[base + 3] = e.w;
            u1[base + 0] = e.x + p.x; u1[base + 1] = e.y + p.y;
            u1[base + 2] = e.z + p.z; u1[base + 3] = e.w + p.w;
        }
    }
    __syncthreads();

    // ---------------- Ph2: P = q @ [Woff | Ww] + bias ----------------
    // thread t: col-group g = t%32 (cols g+32*i, i<9), row-group rg = t/32
    // (rows rg+8m, m<4). 36 accumulators.
    {
        int g  = t & 31;
        int rg = t >> 5;
        float acc[9][4];
        #pragma unroll
        for (int i = 0; i < 9; ++i)
            #pragma unroll
            for (int m = 0; m < 4; ++m) acc[i][m] = 0.f;

        const float* wo_p = Woff + g;
        const float* ww_p = Ww + g;
        for (int k = 0; k < 128; ++k) {
            float q[4];
            #pragma unroll
            for (int m = 0; m < 4; ++m) q[m] = u1[(rg + 8 * m) * 132 + k];
            float wv[9];
            #pragma unroll
            for (int i = 0; i < 6; ++i) wv[i] = wo_p[k * 192 + 32 * i];
            #pragma unroll
            for (int i = 0; i < 3; ++i) wv[6 + i] = ww_p[k * 96 + 32 * i];
            #pragma unroll
            for (int i = 0; i < 9; ++i)
                #pragma unroll
                for (int m = 0; m < 4; ++m)
                    acc[i][m] = fmaf(q[m], wv[i], acc[i][m]);
        }
        #pragma unroll
        for (int i = 0; i < 9; ++i) {
            int c = g + 32 * i;
            float bias = (c < 192) ? boff[c] : bw[c - 192];
            #pragma unroll
            for (int m = 0; m < 4; ++m)
                u2[(rg + 8 * m) * PSS + c] = acc[i][m] + bias;
        }
    }
    __syncthreads();

    // ---------------- Ph2b: softmax over (head, L*P=12) ----------------
    {
        int r = t >> 3, h = t & 7;
        float* pw = &u2[r * PSS + 192 + h * 12];
        float mx = pw[0];
        #pragma unroll
        for (int i = 1; i < 12; ++i) mx = fmaxf(mx, pw[i]);
        float e[12];
        float ssum = 0.f;
        #pragma unroll
        for (int i = 0; i < 12; ++i) { e[i] = __expf(pw[i] - mx); ssum += e[i]; }
        float inv = 1.f / ssum;
        #pragma unroll
        for (int i = 0; i < 12; ++i) pw[i] = e[i] * inv;
    }
    __syncthreads();

    // ---------------- Ph3: bilinear sampling ----------------
    {
        int r = t >> 3, h = t & 7;
        int n = tbase + r;
        float refx = refpix[((size_t)b * N_TOK + n) * 2 + 0];
        float refy = refpix[((size_t)b * N_TOK + n) * 2 + 1];
        float acc16[16];
        #pragma unroll
        for (int i = 0; i < 16; ++i) acc16[i] = 0.f;

        const float* pr = &u2[r * PSS];
        constexpr int LH[3] = {47, 24, 12};
        constexpr int LW[3] = {153, 77, 39};
        constexpr int LS[3] = {0, 7191, 9039};

        #pragma unroll
        for (int l = 0; l < 3; ++l) {
            const int w  = LW[l];
            const int hh = LH[l];
            const __hip_bfloat16* vbase =
                value + ((size_t)b * S_VAL + LS[l]) * 128 + h * 16;
            #pragma unroll
            for (int p = 0; p < 4; ++p) {
                float ox = pr[((h * 3 + l) * 4 + p) * 2 + 0];
                float oy = pr[((h * 3 + l) * 4 + p) * 2 + 1];
                float aw = pr[192 + h * 12 + l * 4 + p];
                float x = (refx + ox / (float)w)  * (float)w  - 0.5f;
                float y = (refy + oy / (float)hh) * (float)hh - 0.5f;
                float x0f = floorf(x), y0f = floorf(y);
                float fx = x - x0f, fy = y - y0f;
                int x0 = (int)x0f, y0 = (int)y0f;
                #pragma unroll
                for (int tap = 0; tap < 4; ++tap) {
                    int dx = tap & 1, dy = tap >> 1;
                    int xi = x0 + dx, yi = y0 + dy;
                    if (xi >= 0 && xi < w && yi >= 0 && yi < hh) {
                        float cw = (dx ? fx : 1.f - fx) * (dy ? fy : 1.f - fy) * aw;
                        const uint4* vp = (const uint4*)(vbase + (size_t)(yi * w + xi) * 128);
                        uint4 qa = vp[0];
                        uint4 qb = vp[1];
#define ACC2(u, i0) do { \
    acc16[i0]     = fmaf(__uint_as_float((u) << 16),        cw, acc16[i0]); \
    acc16[i0 + 1] = fmaf(__uint_as_float((u) & 0xffff0000u), cw, acc16[i0 + 1]); } while (0)
                        ACC2(qa.x, 0);  ACC2(qa.y, 2);  ACC2(qa.z, 4);  ACC2(qa.w, 6);
                        ACC2(qb.x, 8);  ACC2(qb.y, 10); ACC2(qb.z, 12); ACC2(qb.w, 14);
#undef ACC2
                    }
                }
            }
        }
        // write acc to u1 (q is dead)
        float4* ap = (float4*)&u1[r * 132 + h * 16];
        ap[0] = make_float4(acc16[0],  acc16[1],  acc16[2],  acc16[3]);
        ap[1] = make_float4(acc16[4],  acc16[5],  acc16[6],  acc16[7]);
        ap[2] = make_float4(acc16[8],  acc16[9],  acc16[10], acc16[11]);
        ap[3] = make_float4(acc16[12], acc16[13], acc16[14], acc16[15]);
    }
    __syncthreads();

    // ---------------- Ph4: Wo GEMM + residual + LayerNorm + mask ----------------
    {
        int r = t >> 3, j = t & 7;
        int n = tbase + r;
        float acc2[16];
        #pragma unroll
        for (int i = 0; i < 16; ++i) {
            int c = j + 8 * i;
            acc2[i] = bo[c] + es[r * 132 + c];    // bias + identity
        }
        for (int k = 0; k < 128; k += 4) {
            float4 av = *(const float4*)&u1[r * 132 + k];
            #pragma unroll
            for (int i = 0; i < 16; ++i) {
                int c = j + 8 * i;
                acc2[i] = fmaf(av.x, Wo[(k + 0) * 128 + c], acc2[i]);
                acc2[i] = fmaf(av.y, Wo[(k + 1) * 128 + c], acc2[i]);
                acc2[i] = fmaf(av.z, Wo[(k + 2) * 128 + c], acc2[i]);
                acc2[i] = fmaf(av.w, Wo[(k + 3) * 128 + c], acc2[i]);
            }
        }
        // LayerNorm over 128 channels spread across 8 lanes (j) of this token
        float s1 = 0.f, s2 = 0.f;
        #pragma unroll
        for (int i = 0; i < 16; ++i) { s1 += acc2[i]; s2 += acc2[i] * acc2[i]; }
        #pragma unroll
        for (int m = 1; m < 8; m <<= 1) {
            s1 += __shfl_xor(s1, m, 64);
            s2 += __shfl_xor(s2, m, 64);
        }
        float mu   = s1 * (1.f / 128.f);
        float var  = s2 * (1.f / 128.f) - mu * mu;
        float rstd = rsqrtf(var + 1e-5f);
        int   msk  = mask[(size_t)b * N_TOK + n];
        #pragma unroll
        for (int i = 0; i < 16; ++i) {
            int c = j + 8 * i;
            float yv = (acc2[i] - mu) * rstd * ln_g[c] + ln_b[c];
            float ov = msk ? yv : es[r * 132 + c];
            u2[c * 33 + r] = ov;                  // transpose tile (128 x 32, pad 33)
        }
    }
    __syncthreads();

    // ---------------- Ph5: coalesced store to (B, C, N) ----------------
    {
        #pragma unroll
        for (int i = 0; i < 16; ++i) {
            int idx = t + 256 * i;                // 0..4095
            int c = idx >> 5, r = idx & 31;
            out[((size_t)(b * 128 + c)) * N_TOK + tbase + r] = u2[c * 33 + r];
        }
    }
}

// ---------------------------------------------------------------------------
extern "C" void kernel_launch(void* const* d_in, const int* in_sizes, int n_in,
                              void* d_out, int out_size, void* d_ws, size_t ws_size,
                              hipStream_t stream)
{
    (void)n_in; (void)out_size; (void)ws_size;

    const float* embed = (const float*)d_in[0];
    const float* posp  = (const float*)d_in[1];
    const int*   vol   = (const int*)  d_in[2];
    const float* refp  = (const float*)d_in[3];

    // setup_inputs() dict order puts feats LAST; fall back to signature order
    // (feats at 4..6) if in_sizes says index 4 is a big feature map.
    int iW, iF;
    if (in_sizes[4] == C_DIM * C_DIM) { iW = 4; iF = 14; }   // dict order
    else                              { iF = 4; iW = 7;  }   // signature order

    const float* Wv   = (const float*)d_in[iW + 0];
    const float* bv   = (const float*)d_in[iW + 1];
    const float* Woff = (const float*)d_in[iW + 2];
    const float* boff = (const float*)d_in[iW + 3];
    const float* Ww   = (const float*)d_in[iW + 4];
    const float* bw   = (const float*)d_in[iW + 5];
    const float* Wo   = (const float*)d_in[iW + 6];
    const float* bo   = (const float*)d_in[iW + 7];
    const float* lng  = (const float*)d_in[iW + 8];
    const float* lnb  = (const float*)d_in[iW + 9];
    const float* f0   = (const float*)d_in[iF + 0];
    const float* f1   = (const float*)d_in[iF + 1];
    const float* f2   = (const float*)d_in[iF + 2];

    int* maskbuf = (int*)d_ws;
    __hip_bfloat16* value =
        (__hip_bfloat16*)((char*)d_ws + (size_t)B_Q * N_TOK * sizeof(int));

    hipMemsetAsync(maskbuf, 0, (size_t)B_Q * N_TOK * sizeof(int), stream);
    mask_scatter_kernel<<<(B_Q * N_TOK + 255) / 256, 256, 0, stream>>>(vol, maskbuf);
    value_proj_kernel<<<B_Q * 149, 256, 0, stream>>>(f0, f1, f2, Wv, bv, value);
    fused_kernel<<<B_Q * 4096, 256, 0, stream>>>(
        embed, posp, refp, Woff, boff, Ww, bw, Wo, bo, lng, lnb,
        value, maskbuf, (float*)d_out);
}

// Round 2
// 731.453 us; speedup vs baseline: 1.9080x; 1.9080x over previous
//
#include <hip/hip_runtime.h>
#include <hip/hip_bf16.h>
#include <stdint.h>

#define B_Q     2
#define N_TOK   131072        // 128*128*8
#define S_VAL   9507          // 7191 + 1848 + 468
#define PROW    292           // P tile row stride (bf16 units), 288 cols used
#define TROW    36            // transpose tile row stride (f32), 32 used (mult of 4 for b128)

typedef __attribute__((ext_vector_type(8))) short short8;
typedef __attribute__((ext_vector_type(4))) short short4v;
typedef __attribute__((ext_vector_type(4))) float f32x4;

__device__ __forceinline__ unsigned short f32_bf16(float f) {
    unsigned u = __float_as_uint(f);
    u += 0x7FFFu + ((u >> 16) & 1u);           // RNE
    return (unsigned short)(u >> 16);
}
__device__ __forceinline__ float bf16_f32(unsigned short h) {
    return __uint_as_float((unsigned)h << 16);
}

// ---------------------------------------------------------------------------
// K0: scatter voxel mask
// ---------------------------------------------------------------------------
__global__ __launch_bounds__(256) void mask_scatter_kernel(
    const int* __restrict__ vol, int* __restrict__ mask)
{
    int i = blockIdx.x * 256 + threadIdx.x;
    if (i >= B_Q * N_TOK) return;
    int b = i / N_TOK;
    const int* p = vol + (size_t)i * 3;
    int x = p[0], y = p[1], z = p[2];
    if (x >= 0 && x < 128 && y >= 0 && y < 128 && z >= 0 && z < 8)
        mask[b * N_TOK + x * 1024 + y * 8 + z] = 1;
}

// ---------------------------------------------------------------------------
// K_pack: bf16 B-fragment packs for [Woff|Ww] (18 n-tiles) and Wo (8 n-tiles),
// plus concatenated bias288. Fragment element (nt,ks,lane,j) holds
// W[k][n] with n = nt*16 + (lane&15), k = ks*32 + (lane>>4)*8 + j.
// ---------------------------------------------------------------------------
__global__ __launch_bounds__(256) void pack_weights_kernel(
    const float* __restrict__ Woff, const float* __restrict__ boff,
    const float* __restrict__ Ww,   const float* __restrict__ bw,
    const float* __restrict__ Wo,
    unsigned short* __restrict__ wcatp, unsigned short* __restrict__ wop,
    float* __restrict__ bias288)
{
    int idx = blockIdx.x * 256 + threadIdx.x;
    if (idx < 36864) {
        int j = idx & 7, l = (idx >> 3) & 63, ks = (idx >> 9) & 3, nt = idx >> 11;
        int n = nt * 16 + (l & 15);
        int k = ks * 32 + (l >> 4) * 8 + j;
        float v = (n < 192) ? Woff[k * 192 + n] : Ww[k * 96 + (n - 192)];
        wcatp[idx] = f32_bf16(v);
    } else if (idx < 53248) {
        int i2 = idx - 36864;
        int j = i2 & 7, l = (i2 >> 3) & 63, ks = (i2 >> 9) & 3, nt = i2 >> 11;
        int n = nt * 16 + (l & 15);
        int k = ks * 32 + (l >> 4) * 8 + j;
        wop[i2] = f32_bf16(Wo[k * 128 + n]);
    } else if (idx < 53536) {
        int i2 = idx - 53248;
        bias288[i2] = (i2 < 192) ? boff[i2] : bw[i2 - 192];
    }
}

// ---------------------------------------------------------------------------
// K1: value projection -> bf16 value table [b][s][128]
// ---------------------------------------------------------------------------
__global__ __launch_bounds__(256) void value_proj_kernel(
    const float* __restrict__ f0, const float* __restrict__ f1,
    const float* __restrict__ f2,
    const float* __restrict__ Wv, const float* __restrict__ bv,
    __hip_bfloat16* __restrict__ value)
{
    __shared__ float Ast[128 * 68];

    int blk = blockIdx.x;
    int b   = blk / 149;
    int s0  = (blk % 149) * 64;
    int t   = threadIdx.x;

    int j = t & 63;
    int a = t >> 6;
    int s = s0 + j;
    #pragma unroll
    for (int i = 0; i < 32; ++i) {
        int k = a + 4 * i;
        float v = 0.f;
        if (s < S_VAL) {
            if (s < 7191)      v = f0[((size_t)b * 128 + k) * 7191 + s];
            else if (s < 9039) v = f1[((size_t)b * 128 + k) * 1848 + (s - 7191)];
            else               v = f2[((size_t)b * 128 + k) * 468  + (s - 9039)];
        }
        Ast[k * 68 + j] = v;
    }
    __syncthreads();

    int c  = t & 127;
    int rg = t >> 7;
    float acc[32];
    #pragma unroll
    for (int i = 0; i < 32; ++i) acc[i] = 0.f;

    for (int k = 0; k < 128; ++k) {
        float wv = Wv[k * 128 + c];
        const float4* arow = (const float4*)&Ast[k * 68 + rg * 32];
        #pragma unroll
        for (int ii = 0; ii < 8; ++ii) {
            float4 av = arow[ii];
            acc[4 * ii + 0] += av.x * wv;
            acc[4 * ii + 1] += av.y * wv;
            acc[4 * ii + 2] += av.z * wv;
            acc[4 * ii + 3] += av.w * wv;
        }
    }
    float bvc = bv[c];
    #pragma unroll
    for (int i = 0; i < 32; ++i) {
        int s2 = s0 + rg * 32 + i;
        if (s2 < S_VAL)
            value[((size_t)b * S_VAL + s2) * 128 + c] = __float2bfloat16(acc[i] + bvc);
    }
}

// ---------------------------------------------------------------------------
// K2 mega-kernel, MFMA version. 32 tokens/block, 256 threads.
//   Ph1 : q = embed+pos -> bf16 A-frags in LDS
//   Ph2 : P = q @ [Woff|Ww] + bias via MFMA -> bf16 P tile in LDS
//   Ph2b: softmax over (head, 12)
//   Ph3 : bilinear gather -> acc, stored as bf16 A-frags (reuse qA region)
//   Ph4 : acc @ Wo + bo via MFMA -> f32 transpose tile (reuse P region)
//   Ph4b: +embed residual, LayerNorm, mask-select, write back to tile
//   Ph5 : coalesced float4 store to (B, C, N)
// ---------------------------------------------------------------------------
__global__ __launch_bounds__(256, 5) void fused_kernel(
    const float* __restrict__ embed, const float* __restrict__ pos,
    const float* __restrict__ refpix,
    const unsigned short* __restrict__ wcatp,
    const unsigned short* __restrict__ wop,
    const float* __restrict__ bias288,
    const float* __restrict__ bo,
    const float* __restrict__ ln_g, const float* __restrict__ ln_b,
    const __hip_bfloat16* __restrict__ value,
    const int* __restrict__ mask,
    float* __restrict__ out)
{
    __shared__ short qA[4096];                       // 8 KB: q A-frags, then acc A-frags
    __shared__ __align__(16) char r2[32 * PROW * 2]; // 18688 B: P (bf16) / transpose (f32)

    unsigned short* Pb  = (unsigned short*)r2;
    float*          u2t = (float*)r2;                // 128 x TROW f32 (18432 B)
    short8*         qA8 = (short8*)qA;

    int t     = threadIdx.x;
    int bb    = blockIdx.x;
    int b     = bb >> 12;
    int tbase = (bb & 4095) * 32;
    int lane  = t & 63;
    int wvid  = t >> 6;

    // ---------------- Ph1: q -> bf16 A-frags ----------------
    {
        const float4* e4 = (const float4*)(embed + ((size_t)b * N_TOK + tbase) * 128);
        const float4* p4 = (const float4*)(pos   + ((size_t)b * N_TOK + tbase) * 128);
        #pragma unroll
        for (int i = 0; i < 4; ++i) {
            int idx = t + 256 * i;             // 0..1023 float4s, fully coalesced
            int r = idx >> 5, k4 = idx & 31;   // token, 4-channel chunk
            float4 e = e4[idx];
            float4 p = p4[idx];
            short4v q;
            q.x = (short)f32_bf16(e.x + p.x);
            q.y = (short)f32_bf16(e.y + p.y);
            q.z = (short)f32_bf16(e.z + p.z);
            q.w = (short)f32_bf16(e.w + p.w);
            int kg = k4 >> 1;                  // 8-channel fragment chunk
            int mt = r >> 4, ks = kg >> 2;
            int lpos = (r & 15) + ((kg & 3) << 4);
            short4v* dst = (short4v*)((char*)qA +
                (((size_t)(mt * 4 + ks) * 64 + lpos) * 16 + (k4 & 1) * 8));
            *dst = q;
        }
    }
    __syncthreads();

    // ---------------- Ph2: P = q @ [Woff|Ww] (MFMA) ----------------
    {
        int mt = wvid & 1;
        int n0 = (wvid >> 1) * 9;              // 9 n-tiles per wave
        f32x4 acc[9];
        #pragma unroll
        for (int i = 0; i < 9; ++i) acc[i] = (f32x4)(0.f);
        const short8* bp = (const short8*)wcatp;
        #pragma unroll
        for (int ks = 0; ks < 4; ++ks) {
            short8 af = qA8[(mt * 4 + ks) * 64 + lane];
            #pragma unroll
            for (int i = 0; i < 9; ++i) {
                short8 bf = bp[((n0 + i) * 4 + ks) * 64 + lane];
                acc[i] = __builtin_amdgcn_mfma_f32_16x16x32_bf16(af, bf, acc[i], 0, 0, 0);
            }
        }
        int col = lane & 15, quad = lane >> 4;
        #pragma unroll
        for (int i = 0; i < 9; ++i) {
            int n = (n0 + i) * 16 + col;
            float bsv = bias288[n];
            #pragma unroll
            for (int reg = 0; reg < 4; ++reg) {
                int row = mt * 16 + quad * 4 + reg;
                Pb[row * PROW + n] = f32_bf16(acc[i][reg] + bsv);
            }
        }
    }
    __syncthreads();

    // ---------------- Ph2b: softmax (head, 12) — same thread as Ph3 ----------------
    {
        int r = t >> 3, h = t & 7;
        unsigned short* pw = &Pb[r * PROW + 192 + h * 12];
        float e[12];
        #pragma unroll
        for (int i = 0; i < 12; ++i) e[i] = bf16_f32(pw[i]);
        float mx = e[0];
        #pragma unroll
        for (int i = 1; i < 12; ++i) mx = fmaxf(mx, e[i]);
        float ssum = 0.f;
        #pragma unroll
        for (int i = 0; i < 12; ++i) { e[i] = __expf(e[i] - mx); ssum += e[i]; }
        float inv = 1.f / ssum;
        #pragma unroll
        for (int i = 0; i < 12; ++i) pw[i] = f32_bf16(e[i] * inv);
    }
    // no barrier needed: Ph3 thread (r,h) reads exactly what it wrote

    // ---------------- Ph3: bilinear gather ----------------
    {
        int r = t >> 3, h = t & 7;
        int n = tbase + r;
        float2 rp = ((const float2*)refpix)[(size_t)b * N_TOK + n];
        float acc16[16];
        #pragma unroll
        for (int i = 0; i < 16; ++i) acc16[i] = 0.f;

        const unsigned short* pr = &Pb[r * PROW];
        const int LH[3] = {47, 24, 12};
        const int LW[3] = {153, 77, 39};
        const int LS[3] = {0, 7191, 9039};

        #pragma unroll
        for (int l = 0; l < 3; ++l) {
            const int w  = LW[l];
            const int hh = LH[l];
            float bx = rp.x * (float)w  - 0.5f;   // (ref + off/w)*w - 0.5 == ref*w + off - 0.5
            float by = rp.y * (float)hh - 0.5f;
            const __hip_bfloat16* vbase =
                value + ((size_t)b * S_VAL + LS[l]) * 128 + h * 16;
            #pragma unroll
            for (int p = 0; p < 4; ++p) {
                float ox = bf16_f32(pr[((h * 3 + l) * 4 + p) * 2 + 0]);
                float oy = bf16_f32(pr[((h * 3 + l) * 4 + p) * 2 + 1]);
                float aw = bf16_f32(pr[192 + h * 12 + l * 4 + p]);
                float x = bx + ox;
                float y = by + oy;
                float x0f = floorf(x), y0f = floorf(y);
                float fx = x - x0f, fy = y - y0f;
                int x0 = (int)x0f, y0 = (int)y0f;
                #pragma unroll
                for (int tap = 0; tap < 4; ++tap) {
                    int dx = tap & 1, dy = tap >> 1;
                    int xi = x0 + dx, yi = y0 + dy;
                    if (xi >= 0 && xi < w && yi >= 0 && yi < hh) {
                        float cw = (dx ? fx : 1.f - fx) * (dy ? fy : 1.f - fy) * aw;
                        const uint4* vp = (const uint4*)(vbase + (size_t)(yi * w + xi) * 128);
                        uint4 qa = vp[0];
                        uint4 qb = vp[1];
#define ACC2(u, i0) do { \
    acc16[i0]     = fmaf(__uint_as_float((u) << 16),         cw, acc16[i0]); \
    acc16[i0 + 1] = fmaf(__uint_as_float((u) & 0xffff0000u), cw, acc16[i0 + 1]); } while (0)
                        ACC2(qa.x, 0);  ACC2(qa.y, 2);  ACC2(qa.z, 4);  ACC2(qa.w, 6);
                        ACC2(qb.x, 8);  ACC2(qb.y, 10); ACC2(qb.z, 12); ACC2(qb.w, 14);
#undef ACC2
                    }
                }
            }
        }
        // store acc as bf16 A-frags into qA region (q is dead past barrier 2)
        short8 v0, v1;
        #pragma unroll
        for (int j2 = 0; j2 < 8; ++j2) {
            v0[j2] = (short)f32_bf16(acc16[j2]);
            v1[j2] = (short)f32_bf16(acc16[8 + j2]);
        }
        int mt = r >> 4, rl = r & 15;
        int kg0 = 2 * h, kg1 = 2 * h + 1;
        qA8[(mt * 4 + (kg0 >> 2)) * 64 + rl + ((kg0 & 3) << 4)] = v0;
        qA8[(mt * 4 + (kg1 >> 2)) * 64 + rl + ((kg1 & 3) << 4)] = v1;
    }
    __syncthreads();

    // ---------------- Ph4: acc @ Wo + bo (MFMA) -> transpose tile ----------------
    {
        int mt  = wvid & 1;
        int nt0 = (wvid >> 1) * 4;
        f32x4 acc[4];
        #pragma unroll
        for (int i = 0; i < 4; ++i) acc[i] = (f32x4)(0.f);
        const short8* bp = (const short8*)wop;
        #pragma unroll
        for (int ks = 0; ks < 4; ++ks) {
            short8 af = qA8[(mt * 4 + ks) * 64 + lane];
            #pragma unroll
            for (int i = 0; i < 4; ++i) {
                short8 bf = bp[((nt0 + i) * 4 + ks) * 64 + lane];
                acc[i] = __builtin_amdgcn_mfma_f32_16x16x32_bf16(af, bf, acc[i], 0, 0, 0);
            }
        }
        int col = lane & 15, quad = lane >> 4;
        #pragma unroll
        for (int i = 0; i < 4; ++i) {
            int c = (nt0 + i) * 16 + col;
            float bc = bo[c];
            #pragma unroll
            for (int reg = 0; reg < 4; ++reg) {
                int row = mt * 16 + quad * 4 + reg;
                u2t[c * TROW + row] = acc[i][reg] + bc;
            }
        }
    }
    __syncthreads();

    // ---------------- Ph4b: residual + LayerNorm + mask ----------------
    {
        int r = t >> 3, j = t & 7;
        int n = tbase + r;
        const float* eb = embed + ((size_t)b * N_TOK + n) * 128;
        float v[16], ev[16];
        float s1 = 0.f, s2 = 0.f;
        #pragma unroll
        for (int i = 0; i < 16; ++i) {
            int c = j + 8 * i;
            float e = eb[c];
            float x = u2t[c * TROW + r] + e;
            ev[i] = e; v[i] = x;
            s1 += x; s2 += x * x;
        }
        #pragma unroll
        for (int m = 1; m < 8; m <<= 1) {
            s1 += __shfl_xor(s1, m, 64);
            s2 += __shfl_xor(s2, m, 64);
        }
        float mu   = s1 * (1.f / 128.f);
        float var  = s2 * (1.f / 128.f) - mu * mu;
        float rstd = rsqrtf(var + 1e-5f);
        int   msk  = mask[(size_t)b * N_TOK + n];
        #pragma unroll
        for (int i = 0; i < 16; ++i) {
            int c = j + 8 * i;
            float yv = (v[i] - mu) * rstd * ln_g[c] + ln_b[c];
            u2t[c * TROW + r] = msk ? yv : ev[i];
        }
    }
    __syncthreads();

    // ---------------- Ph5: coalesced float4 store to (B, C, N) ----------------
    {
        #pragma unroll
        for (int i = 0; i < 4; ++i) {
            int idx = t + 256 * i;             // 0..1023
            int c = idx >> 3, r4 = idx & 7;
            float4 vv = *(const float4*)&u2t[c * TROW + r4 * 4];
            *(float4*)&out[((size_t)(b * 128 + c)) * N_TOK + tbase + r4 * 4] = vv;
        }
    }
}

// ---------------------------------------------------------------------------
extern "C" void kernel_launch(void* const* d_in, const int* in_sizes, int n_in,
                              void* d_out, int out_size, void* d_ws, size_t ws_size,
                              hipStream_t stream)
{
    (void)n_in; (void)out_size; (void)ws_size;

    const float* embed = (const float*)d_in[0];
    const float* posp  = (const float*)d_in[1];
    const int*   vol   = (const int*)  d_in[2];
    const float* refp  = (const float*)d_in[3];

    int iW, iF;
    if (in_sizes[4] == 128 * 128) { iW = 4; iF = 14; }   // dict order
    else                          { iF = 4; iW = 7;  }   // signature order

    const float* Wv   = (const float*)d_in[iW + 0];
    const float* bv   = (const float*)d_in[iW + 1];
    const float* Woff = (const float*)d_in[iW + 2];
    const float* boff = (const float*)d_in[iW + 3];
    const float* Ww   = (const float*)d_in[iW + 4];
    const float* bw   = (const float*)d_in[iW + 5];
    const float* Wo   = (const float*)d_in[iW + 6];
    const float* bo   = (const float*)d_in[iW + 7];
    const float* lng  = (const float*)d_in[iW + 8];
    const float* lnb  = (const float*)d_in[iW + 9];
    const float* f0   = (const float*)d_in[iF + 0];
    const float* f1   = (const float*)d_in[iF + 1];
    const float* f2   = (const float*)d_in[iF + 2];

    char* ws = (char*)d_ws;
    int*            maskbuf = (int*)ws;                                   // 1 MB
    __hip_bfloat16* value   = (__hip_bfloat16*)(ws + 1048576);            // 4.87 MB
    unsigned short* wcatp   = (unsigned short*)(ws + 1048576 + 4867584);  // 73728 B
    unsigned short* wop     = (unsigned short*)(ws + 1048576 + 4867584 + 73728); // 32768 B
    float*          bias288 = (float*)(ws + 1048576 + 4867584 + 73728 + 32768); // 1152 B

    hipMemsetAsync(maskbuf, 0, (size_t)B_Q * N_TOK * sizeof(int), stream);
    mask_scatter_kernel<<<(B_Q * N_TOK + 255) / 256, 256, 0, stream>>>(vol, maskbuf);
    pack_weights_kernel<<<(53536 + 255) / 256, 256, 0, stream>>>(
        Woff, boff, Ww, bw, Wo, wcatp, wop, bias288);
    value_proj_kernel<<<B_Q * 149, 256, 0, stream>>>(f0, f1, f2, Wv, bv, value);
    fused_kernel<<<B_Q * 4096, 256, 0, stream>>>(
        embed, posp, refp, wcatp, wop, bias288, bo, lng, lnb,
        value, maskbuf, (float*)d_out);
}